// Round 8
// baseline (240.736 us; speedup 1.0000x reference)
//
#include <hip/hip_runtime.h>
#include <hip/hip_bf16.h>
#include <float.h>

#define N_NODES 100000
#define N_EDGES 1600000
#define HEADS 4
#define OUT_F 32
#define NEG_SLOPE 0.2f
#define EXP_SHIFT 8.0f

#define NB 782      // bins of 128 nodes: bin = dst >> 7 (782*128 = 100096)
#define NT 391      // tiles of 4096 edges
#define PCAP 4096   // fixed per-bin capacity in ebuf/esrc (mean 2046, +45 sigma)
#define SCAP 3072   // k_bucket LDS stage (mean 2046, +23 sigma)

typedef __attribute__((ext_vector_type(8))) short short8;
typedef __attribute__((ext_vector_type(4))) float f32x4;

__device__ __forceinline__ int enc_f(float f) {
    int b = __float_as_int(f);
    return b >= 0 ? b : b ^ 0x7fffffff;
}
__device__ __forceinline__ float dec_f(int b) {
    return __int_as_float(b >= 0 ? b : b ^ 0x7fffffff);
}
#define ENC_NEG_FLT_MAX ((int)0x80800000)   // enc_f(-FLT_MAX)

__device__ __forceinline__ unsigned short f2bf(float f) {
    unsigned int u = __float_as_uint(f);
    u += 0x7fff + ((u >> 16) & 1);   // round-to-nearest-even
    return (unsigned short)(u >> 16);
}

// ---------------- prep: blocks [0,NT) per-tile coarse histogram;
//                  blocks [NT,NT+32) transpose W->Wt bf16; S init
__global__ __launch_bounds__(256) void k_prep(const int* __restrict__ ei,
                                              const float* __restrict__ W,
                                              unsigned short* __restrict__ Wt,
                                              int* __restrict__ hist,
                                              float* __restrict__ S) {
    __shared__ int lh[NB];
    int b = blockIdx.x, tid = threadIdx.x;
    if (b < NT) {
        for (int i = tid; i < NB; i += 256) lh[i] = 0;
        __syncthreads();
        const int4* d4 = (const int4*)(ei + N_EDGES);
        int base4 = b * 1024;
#pragma unroll
        for (int it = 0; it < 4; it++) {
            int i4 = base4 + tid + 256 * it;
            if (i4 < N_EDGES / 4) {
                int4 d = d4[i4];
                atomicAdd(&lh[d.x >> 7], 1);
                atomicAdd(&lh[d.y >> 7], 1);
                atomicAdd(&lh[d.z >> 7], 1);
                atomicAdd(&lh[d.w >> 7], 1);
            }
        }
        __syncthreads();
        for (int i = tid; i < NB; i += 256) hist[b * NB + i] = lh[i];
    } else {
        int idx = (b - NT) * 256 + tid;    // 0..8191 ushort2 pairs
        int n = idx & 127, k2 = idx >> 7;  // k2 in 0..63
        float w0 = W[(size_t)(2 * k2) * 128 + n];
        float w1 = W[(size_t)(2 * k2 + 1) * 128 + n];
        *(ushort2*)&Wt[(size_t)n * 128 + 2 * k2] = make_ushort2(f2bf(w0), f2bf(w1));
        if (b == NT && tid < 4) S[tid] = 0.0f;
    }
}

// ---------------- GEMM: Whb(bf16, rows 0..N_NODES incl zero pad row) = h @ W
// 512 thr (8 waves), 128 rows/block, A-fragments loaded direct from global.
__global__ __launch_bounds__(512) void k_gemm(const float* __restrict__ hp,
                                              const unsigned short* __restrict__ Wt,
                                              const float* __restrict__ av,
                                              unsigned short* __restrict__ Whb,
                                              float* __restrict__ s_src,
                                              float* __restrict__ s_dst) {
    __shared__ short wsB[128][136];
    int tid = threadIdx.x;
    int rowBase = blockIdx.x * 128;

    const short8* Wt8 = (const short8*)Wt;
#pragma unroll
    for (int i = 0; i < 4; i++) {
        int idx = tid + 512 * i;          // 0..2047
        int n = idx >> 4, ch = idx & 15;
        *(short8*)&wsB[n][ch * 8] = Wt8[idx];
    }
    __syncthreads();

    int lane = tid & 63;
    int wv = tid >> 6;                    // 0..7
    int l16 = lane & 15, quad = lane >> 4;

    // A-frag: A[m=l16][k=quad*8+j]; global row owned by this lane:
    int arow = rowBase + wv * 16 + l16;
    bool valid = arow < N_NODES;
    const float* hrow = hp + (size_t)arow * 128;
    short8 afr[4];
#pragma unroll
    for (int k4 = 0; k4 < 4; k4++) {
        float4 u0 = valid ? *(const float4*)&hrow[k4 * 32 + quad * 8]
                          : make_float4(0.f, 0.f, 0.f, 0.f);
        float4 u1 = valid ? *(const float4*)&hrow[k4 * 32 + quad * 8 + 4]
                          : make_float4(0.f, 0.f, 0.f, 0.f);
        afr[k4] = (short8){(short)f2bf(u0.x), (short)f2bf(u0.y),
                           (short)f2bf(u0.z), (short)f2bf(u0.w),
                           (short)f2bf(u1.x), (short)f2bf(u1.y),
                           (short)f2bf(u1.z), (short)f2bf(u1.w)};
    }

    f32x4 acc[8];
#pragma unroll
    for (int nt = 0; nt < 8; nt++) {
        acc[nt] = (f32x4){0.f, 0.f, 0.f, 0.f};
#pragma unroll
        for (int k4 = 0; k4 < 4; k4++) {
            short8 bfr = *(const short8*)&wsB[nt * 16 + l16][k4 * 32 + quad * 8];
            acc[nt] = __builtin_amdgcn_mfma_f32_16x16x32_bf16(afr[k4], bfr, acc[nt], 0, 0, 0);
        }
    }

    // C/D: col = nt*16 + l16, row = rowBase + wv*16 + quad*4 + r
    int row0 = rowBase + wv * 16 + quad * 4;
#pragma unroll
    for (int r = 0; r < 4; r++) {
        int row = row0 + r;
        if (row <= N_NODES) {             // row N_NODES = zero pad row (acc==0 there)
#pragma unroll
            for (int nt = 0; nt < 8; nt++)
                Whb[(size_t)row * 128 + nt * 16 + l16] = f2bf(acc[nt][r]);
        }
    }

    // fused s_src/s_dst from fp32 accumulators
    float ps[4][4], pd[4][4];
#pragma unroll
    for (int h = 0; h < 4; h++) {
        float a0s = av[h * 64 + l16];
        float a1s = av[h * 64 + 16 + l16];
        float a0d = av[h * 64 + 32 + l16];
        float a1d = av[h * 64 + 48 + l16];
#pragma unroll
        for (int r = 0; r < 4; r++) {
            ps[h][r] = acc[2 * h][r] * a0s + acc[2 * h + 1][r] * a1s;
            pd[h][r] = acc[2 * h][r] * a0d + acc[2 * h + 1][r] * a1d;
        }
    }
#pragma unroll
    for (int h = 0; h < 4; h++)
#pragma unroll
        for (int r = 0; r < 4; r++) {
#pragma unroll
            for (int off = 1; off < 16; off <<= 1) {
                ps[h][r] += __shfl_xor(ps[h][r], off);
                pd[h][r] += __shfl_xor(pd[h][r], off);
            }
        }
    if (l16 < 4) {
#pragma unroll
        for (int r = 0; r < 4; r++) {
            int row = row0 + r;
            if (row < N_NODES) {
                float vs = (l16 == 0) ? ps[0][r] : (l16 == 1) ? ps[1][r]
                         : (l16 == 2) ? ps[2][r] : ps[3][r];
                float vd = (l16 == 0) ? pd[0][r] : (l16 == 1) ? pd[1][r]
                         : (l16 == 2) ? pd[2][r] : pd[3][r];
                s_src[row * 4 + l16] = vs;
                s_dst[row * 4 + l16] = vd;
            }
        }
    }
}

// ---------------- per-bin scan over tiles -> tileoff (excl), bin_total
__global__ __launch_bounds__(512) void k_scan(const int* __restrict__ hist,
                                              int* __restrict__ tileoff,
                                              int* __restrict__ bin_total) {
    int b = blockIdx.x, tid = threadIdx.x;
    int val = (tid < NT) ? hist[tid * NB + b] : 0;
    int lane = tid & 63, wv = tid >> 6;
    int v = val;
#pragma unroll
    for (int off = 1; off < 64; off <<= 1) {
        int t = __shfl_up(v, off);
        if (lane >= off) v += t;
    }
    __shared__ int wtot[8], woff[8];
    if (lane == 63) wtot[wv] = v;
    __syncthreads();
    if (tid == 0) { int s = 0; for (int i = 0; i < 8; i++) { woff[i] = s; s += wtot[i]; } }
    __syncthreads();
    int incl = v + woff[wv];
    if (tid < NT) tileoff[tid * NB + b] = incl - val;
    if (tid == NT - 1) bin_total[b] = incl;
}

// ---------------- scatter packed (localdst,src) records; bin base = b*PCAP
__global__ __launch_bounds__(256) void k_scat(const int* __restrict__ ei,
                                              const int* __restrict__ tileoff,
                                              int* __restrict__ ebuf) {
    __shared__ int lcur[NB];
    int tid = threadIdx.x, tile = blockIdx.x;
    for (int i = tid; i < NB; i += 256) lcur[i] = i * PCAP + tileoff[tile * NB + i];
    __syncthreads();
    const int4* s4 = (const int4*)ei;
    const int4* d4 = (const int4*)(ei + N_EDGES);
    int base4 = tile * 1024;
#pragma unroll
    for (int it = 0; it < 4; it++) {
        int i4 = base4 + tid + 256 * it;
        if (i4 < N_EDGES / 4) {
            int4 s = s4[i4];
            int4 d = d4[i4];
            int p;
            p = atomicAdd(&lcur[d.x >> 7], 1); ebuf[p] = s.x | ((d.x & 127) << 17);
            p = atomicAdd(&lcur[d.y >> 7], 1); ebuf[p] = s.y | ((d.y & 127) << 17);
            p = atomicAdd(&lcur[d.z >> 7], 1); ebuf[p] = s.z | ((d.z & 127) << 17);
            p = atomicAdd(&lcur[d.w >> 7], 1); ebuf[p] = s.w | ((d.w & 127) << 17);
        }
    }
}

// ---------------- fused bucket: cnt/start (padded x4), node-sort -> esrc,
//                  segment-max, exp(score-EXP_SHIFT) -> expv, partial S
__global__ __launch_bounds__(256) void k_bucket(const int* __restrict__ bin_total,
                                                const int* __restrict__ ebuf,
                                                int* __restrict__ esrc,
                                                int* __restrict__ cnt,
                                                int* __restrict__ start,
                                                const float* __restrict__ s_src,
                                                const float* __restrict__ s_dst,
                                                float* __restrict__ expv,
                                                float* __restrict__ S) {
    __shared__ int stage[SCAP];
    __shared__ int lh[128];
    __shared__ int lcur[128];
    __shared__ int nm[4][128];
    __shared__ int wq;
    __shared__ float sred[4][4];
    int b = blockIdx.x, tid = threadIdx.x;
    int base = b * PCAP;
    int total = bin_total[b];
    if (total > SCAP) total = SCAP;   // unreachable (+23 sigma)
    if (tid < 128) {
        lh[tid] = 0;
        nm[0][tid] = ENC_NEG_FLT_MAX; nm[1][tid] = ENC_NEG_FLT_MAX;
        nm[2][tid] = ENC_NEG_FLT_MAX; nm[3][tid] = ENC_NEG_FLT_MAX;
    }
    __syncthreads();
    for (int i = tid; i < total; i += 256) {
        int rec = ebuf[base + i];
        stage[i] = rec;
        atomicAdd(&lh[(rec >> 17) & 127], 1);
    }
    __syncthreads();
    int lane = tid & 63;
    int val = 0, padded = 0, gpos = 0;
    if (tid < 128) {
        val = lh[tid];
        padded = (val + 3) & ~3;          // pad segment to x4 with zero-row srcs
        int v = padded;
#pragma unroll
        for (int off = 1; off < 64; off <<= 1) {
            int t = __shfl_up(v, off);
            if (lane >= off) v += t;
        }
        if (tid == 63) wq = v;
        __syncthreads();
        gpos = base + v - padded + ((tid >= 64) ? wq : 0);
        int node = b * 128 + tid;
        if (node < N_NODES) { cnt[node] = padded; start[node] = gpos; }
        lcur[tid] = gpos;
    } else {
        __syncthreads();
    }
    __syncthreads();
    for (int i = tid; i < total; i += 256) {
        int rec = stage[i];
        int src = rec & 0x1FFFF;
        int ld = (rec >> 17) & 127;
        int p = atomicAdd(&lcur[ld], 1);
        esrc[p] = src;
        float4 sv = ((const float4*)s_src)[src];
        atomicMax(&nm[0][ld], enc_f(sv.x));
        atomicMax(&nm[1][ld], enc_f(sv.y));
        atomicMax(&nm[2][ld], enc_f(sv.z));
        atomicMax(&nm[3][ld], enc_f(sv.w));
    }
    __syncthreads();
    float4 e4 = make_float4(0.f, 0.f, 0.f, 0.f);
    if (tid < 128) {
        for (int k = val; k < padded; k++) esrc[gpos + k] = N_NODES;  // zero-row pads
        int node = b * 128 + tid;
        if (node < N_NODES) {
            float4 d = ((const float4*)s_dst)[node];
            float x;
            x = dec_f(nm[0][tid]) + d.x; x = x > 0.f ? x : NEG_SLOPE * x; e4.x = __expf(x - EXP_SHIFT);
            x = dec_f(nm[1][tid]) + d.y; x = x > 0.f ? x : NEG_SLOPE * x; e4.y = __expf(x - EXP_SHIFT);
            x = dec_f(nm[2][tid]) + d.z; x = x > 0.f ? x : NEG_SLOPE * x; e4.z = __expf(x - EXP_SHIFT);
            x = dec_f(nm[3][tid]) + d.w; x = x > 0.f ? x : NEG_SLOPE * x; e4.w = __expf(x - EXP_SHIFT);
            ((float4*)expv)[node] = e4;
        }
    }
#pragma unroll
    for (int off = 32; off; off >>= 1) {
        e4.x += __shfl_xor(e4.x, off);
        e4.y += __shfl_xor(e4.y, off);
        e4.z += __shfl_xor(e4.z, off);
        e4.w += __shfl_xor(e4.w, off);
    }
    int wv = tid >> 6;
    if (lane == 0) { sred[wv][0] = e4.x; sred[wv][1] = e4.y; sred[wv][2] = e4.z; sred[wv][3] = e4.w; }
    __syncthreads();
    if (tid < 4)
        atomicAdd(&S[tid], sred[0][tid] + sred[1][tid] + sred[2][tid] + sred[3][tid]);
}

// ---------------- aggregate: one wave per node; scalar walk; deg is x4-padded
__global__ __launch_bounds__(256) void k_agg(const unsigned int* __restrict__ Whb32,
                                             const int* __restrict__ esrc,
                                             const int* __restrict__ start,
                                             const int* __restrict__ cnt,
                                             const float* __restrict__ expv,
                                             const float* __restrict__ S,
                                             float* __restrict__ out) {
    int node = (blockIdx.x * 256 + threadIdx.x) >> 6;
    if (node >= N_NODES) return;
    int lane = threadIdx.x & 63;
    int base = __builtin_amdgcn_readfirstlane(start[node]);
    int deg  = __builtin_amdgcn_readfirstlane(cnt[node]);
    const unsigned int* Wl = Whb32 + lane;
    float accx = 0.f, accy = 0.f;
    int i = 0;
    for (; i + 16 <= deg; i += 16) {
        unsigned int v[16];
#pragma unroll
        for (int j = 0; j < 16; j++) {
            int s = esrc[base + i + j];
            v[j] = Wl[(size_t)s * 64];
        }
#pragma unroll
        for (int j = 0; j < 16; j++) {
            accx += __uint_as_float(v[j] << 16);
            accy += __uint_as_float(v[j] & 0xffff0000u);
        }
    }
    for (; i < deg; i += 4) {
        unsigned int v[4];
#pragma unroll
        for (int j = 0; j < 4; j++) {
            int s = esrc[base + i + j];
            v[j] = Wl[(size_t)s * 64];
        }
#pragma unroll
        for (int j = 0; j < 4; j++) {
            accx += __uint_as_float(v[j] << 16);
            accy += __uint_as_float(v[j] & 0xffff0000u);
        }
    }
    int head = lane >> 4;
    float attn = expv[node * 4 + head] / S[head];
    ((float2*)out)[(size_t)node * 64 + lane] = make_float2(accx * attn, accy * attn);
}

extern "C" void kernel_launch(void* const* d_in, const int* in_sizes, int n_in,
                              void* d_out, int out_size, void* d_ws, size_t ws_size,
                              hipStream_t stream) {
    const float* h  = (const float*)d_in[0];
    const int*   ei = (const int*)d_in[1];
    const float* W  = (const float*)d_in[2];
    const float* a  = (const float*)d_in[3];
    float* out = (float*)d_out;

    char* ws = (char*)d_ws;
    unsigned short* Whb = (unsigned short*)(ws);     // 25,600,256 B (100001 rows bf16)
    float* s_src     = (float*)(ws + 25600256);      //  1,600,000
    float* s_dst     = (float*)(ws + 27200256);      //  1,600,000
    float* expv      = (float*)(ws + 28800256);      //  1,600,000
    int*   cnt       = (int*)  (ws + 30400256);      //    400,000
    int*   start     = (int*)  (ws + 30800256);      //    400,000
    int*   ebuf      = (int*)  (ws + 31200256);      // 12,812,288 (NB*PCAP*4)
    int*   esrc      = (int*)  (ws + 44012544);      // 12,812,288
    int*   hist      = (int*)  (ws + 56824832);      //  1,223,048 (NT*NB*4)
    int*   tileoff   = (int*)  (ws + 58047880);      //  1,223,048
    int*   bin_total = (int*)  (ws + 59270928);      //      3,128
    float* S         = (float*)(ws + 59274056);      //         16
    // Wt (32 KB bf16) aliases ebuf: live only k_prep -> k_gemm, before k_scat
    unsigned short* Wt = (unsigned short*)ebuf;

    k_prep<<<NT + 32, 256, 0, stream>>>(ei, W, Wt, hist, S);
    k_gemm<<<782, 512, 0, stream>>>(h, Wt, a, Whb, s_src, s_dst);
    k_scan<<<NB, 512, 0, stream>>>(hist, tileoff, bin_total);
    k_scat<<<NT, 256, 0, stream>>>(ei, tileoff, ebuf);
    k_bucket<<<NB, 256, 0, stream>>>(bin_total, ebuf, esrc, cnt, start,
                                     s_src, s_dst, expv, S);
    k_agg<<<25000, 256, 0, stream>>>((const unsigned int*)Whb, esrc, start, cnt, expv, S, out);
}

// Round 9
// 235.686 us; speedup vs baseline: 1.0214x; 1.0214x over previous
//
#include <hip/hip_runtime.h>
#include <hip/hip_bf16.h>
#include <float.h>

#define N_NODES 100000
#define N_EDGES 1600000
#define HEADS 4
#define OUT_F 32
#define NEG_SLOPE 0.2f
#define EXP_SHIFT 8.0f

#define NB 782      // bins of 128 nodes: bin = dst >> 7 (782*128 = 100096)
#define NT 391      // tiles of 4096 edges
#define PCAP 4096   // fixed per-bin capacity in ebuf/esrc (mean 2046, +45 sigma)
#define SCAP 3072   // k_bucket LDS stage (mean 2046, +23 sigma; pads need total<=2688)

typedef __attribute__((ext_vector_type(8))) short short8;
typedef __attribute__((ext_vector_type(4))) float f32x4;

__device__ __forceinline__ unsigned short f2bf(float f) {
    unsigned int u = __float_as_uint(f);
    u += 0x7fff + ((u >> 16) & 1);   // round-to-nearest-even
    return (unsigned short)(u >> 16);
}

// ---------------- prep: blocks [0,NT) per-tile coarse histogram;
//                  blocks [NT,NT+32) transpose W->Wt bf16; S=0; s_src sentinel
__global__ __launch_bounds__(256) void k_prep(const int* __restrict__ ei,
                                              const float* __restrict__ W,
                                              unsigned short* __restrict__ Wt,
                                              int* __restrict__ hist,
                                              float* __restrict__ S,
                                              float* __restrict__ s_src) {
    __shared__ int lh[NB];
    int b = blockIdx.x, tid = threadIdx.x;
    if (b < NT) {
        for (int i = tid; i < NB; i += 256) lh[i] = 0;
        __syncthreads();
        const int4* d4 = (const int4*)(ei + N_EDGES);
        int base4 = b * 1024;
#pragma unroll
        for (int it = 0; it < 4; it++) {
            int i4 = base4 + tid + 256 * it;
            if (i4 < N_EDGES / 4) {
                int4 d = d4[i4];
                atomicAdd(&lh[d.x >> 7], 1);
                atomicAdd(&lh[d.y >> 7], 1);
                atomicAdd(&lh[d.z >> 7], 1);
                atomicAdd(&lh[d.w >> 7], 1);
            }
        }
        __syncthreads();
        for (int i = tid; i < NB; i += 256) hist[b * NB + i] = lh[i];
    } else {
        int idx = (b - NT) * 256 + tid;    // 0..8191 ushort2 pairs
        int n = idx & 127, k2 = idx >> 7;  // k2 in 0..63
        float w0 = W[(size_t)(2 * k2) * 128 + n];
        float w1 = W[(size_t)(2 * k2 + 1) * 128 + n];
        *(ushort2*)&Wt[(size_t)n * 128 + 2 * k2] = make_ushort2(f2bf(w0), f2bf(w1));
        if (b == NT) {
            if (tid < 4) S[tid] = 0.0f;
            if (tid >= 4 && tid < 8) s_src[N_NODES * 4 + (tid - 4)] = -1e30f;
        }
    }
}

// ---------------- GEMM: Whb(bf16, rows 0..N_NODES incl zero pad row) = h @ W
__global__ __launch_bounds__(512) void k_gemm(const float* __restrict__ hp,
                                              const unsigned short* __restrict__ Wt,
                                              const float* __restrict__ av,
                                              unsigned short* __restrict__ Whb,
                                              float* __restrict__ s_src,
                                              float* __restrict__ s_dst) {
    __shared__ short wsB[128][136];
    int tid = threadIdx.x;
    int rowBase = blockIdx.x * 128;

    const short8* Wt8 = (const short8*)Wt;
#pragma unroll
    for (int i = 0; i < 4; i++) {
        int idx = tid + 512 * i;          // 0..2047
        int n = idx >> 4, ch = idx & 15;
        *(short8*)&wsB[n][ch * 8] = Wt8[idx];
    }
    __syncthreads();

    int lane = tid & 63;
    int wv = tid >> 6;                    // 0..7
    int l16 = lane & 15, quad = lane >> 4;

    int arow = rowBase + wv * 16 + l16;
    bool valid = arow < N_NODES;
    const float* hrow = hp + (size_t)arow * 128;
    short8 afr[4];
#pragma unroll
    for (int k4 = 0; k4 < 4; k4++) {
        float4 u0 = valid ? *(const float4*)&hrow[k4 * 32 + quad * 8]
                          : make_float4(0.f, 0.f, 0.f, 0.f);
        float4 u1 = valid ? *(const float4*)&hrow[k4 * 32 + quad * 8 + 4]
                          : make_float4(0.f, 0.f, 0.f, 0.f);
        afr[k4] = (short8){(short)f2bf(u0.x), (short)f2bf(u0.y),
                           (short)f2bf(u0.z), (short)f2bf(u0.w),
                           (short)f2bf(u1.x), (short)f2bf(u1.y),
                           (short)f2bf(u1.z), (short)f2bf(u1.w)};
    }

    f32x4 acc[8];
#pragma unroll
    for (int nt = 0; nt < 8; nt++) {
        acc[nt] = (f32x4){0.f, 0.f, 0.f, 0.f};
#pragma unroll
        for (int k4 = 0; k4 < 4; k4++) {
            short8 bfr = *(const short8*)&wsB[nt * 16 + l16][k4 * 32 + quad * 8];
            acc[nt] = __builtin_amdgcn_mfma_f32_16x16x32_bf16(afr[k4], bfr, acc[nt], 0, 0, 0);
        }
    }

    int row0 = rowBase + wv * 16 + quad * 4;
#pragma unroll
    for (int r = 0; r < 4; r++) {
        int row = row0 + r;
        if (row <= N_NODES) {             // row N_NODES = zero pad row (acc==0 there)
#pragma unroll
            for (int nt = 0; nt < 8; nt++)
                Whb[(size_t)row * 128 + nt * 16 + l16] = f2bf(acc[nt][r]);
        }
    }

    float ps[4][4], pd[4][4];
#pragma unroll
    for (int h = 0; h < 4; h++) {
        float a0s = av[h * 64 + l16];
        float a1s = av[h * 64 + 16 + l16];
        float a0d = av[h * 64 + 32 + l16];
        float a1d = av[h * 64 + 48 + l16];
#pragma unroll
        for (int r = 0; r < 4; r++) {
            ps[h][r] = acc[2 * h][r] * a0s + acc[2 * h + 1][r] * a1s;
            pd[h][r] = acc[2 * h][r] * a0d + acc[2 * h + 1][r] * a1d;
        }
    }
#pragma unroll
    for (int h = 0; h < 4; h++)
#pragma unroll
        for (int r = 0; r < 4; r++) {
#pragma unroll
            for (int off = 1; off < 16; off <<= 1) {
                ps[h][r] += __shfl_xor(ps[h][r], off);
                pd[h][r] += __shfl_xor(pd[h][r], off);
            }
        }
    if (l16 < 4) {
#pragma unroll
        for (int r = 0; r < 4; r++) {
            int row = row0 + r;
            if (row < N_NODES) {
                float vs = (l16 == 0) ? ps[0][r] : (l16 == 1) ? ps[1][r]
                         : (l16 == 2) ? ps[2][r] : ps[3][r];
                float vd = (l16 == 0) ? pd[0][r] : (l16 == 1) ? pd[1][r]
                         : (l16 == 2) ? pd[2][r] : pd[3][r];
                s_src[row * 4 + l16] = vs;
                s_dst[row * 4 + l16] = vd;
            }
        }
    }
}

// ---------------- per-bin scan over tiles -> tileoff (excl), bin_total
__global__ __launch_bounds__(512) void k_scan(const int* __restrict__ hist,
                                              int* __restrict__ tileoff,
                                              int* __restrict__ bin_total) {
    int b = blockIdx.x, tid = threadIdx.x;
    int val = (tid < NT) ? hist[tid * NB + b] : 0;
    int lane = tid & 63, wv = tid >> 6;
    int v = val;
#pragma unroll
    for (int off = 1; off < 64; off <<= 1) {
        int t = __shfl_up(v, off);
        if (lane >= off) v += t;
    }
    __shared__ int wtot[8], woff[8];
    if (lane == 63) wtot[wv] = v;
    __syncthreads();
    if (tid == 0) { int s = 0; for (int i = 0; i < 8; i++) { woff[i] = s; s += wtot[i]; } }
    __syncthreads();
    int incl = v + woff[wv];
    if (tid < NT) tileoff[tid * NB + b] = incl - val;
    if (tid == NT - 1) bin_total[b] = incl;
}

// ---------------- scatter packed (localdst,src) records; bin base = b*PCAP
__global__ __launch_bounds__(256) void k_scat(const int* __restrict__ ei,
                                              const int* __restrict__ tileoff,
                                              int* __restrict__ ebuf) {
    __shared__ int lcur[NB];
    int tid = threadIdx.x, tile = blockIdx.x;
    for (int i = tid; i < NB; i += 256) lcur[i] = i * PCAP + tileoff[tile * NB + i];
    __syncthreads();
    const int4* s4 = (const int4*)ei;
    const int4* d4 = (const int4*)(ei + N_EDGES);
    int base4 = tile * 1024;
#pragma unroll
    for (int it = 0; it < 4; it++) {
        int i4 = base4 + tid + 256 * it;
        if (i4 < N_EDGES / 4) {
            int4 s = s4[i4];
            int4 d = d4[i4];
            int p;
            p = atomicAdd(&lcur[d.x >> 7], 1); ebuf[p] = s.x | ((d.x & 127) << 17);
            p = atomicAdd(&lcur[d.y >> 7], 1); ebuf[p] = s.y | ((d.y & 127) << 17);
            p = atomicAdd(&lcur[d.z >> 7], 1); ebuf[p] = s.z | ((d.z & 127) << 17);
            p = atomicAdd(&lcur[d.w >> 7], 1); ebuf[p] = s.w | ((d.w & 127) << 17);
        }
    }
}

// ---------------- bucket (rewritten, no atomicMax, coalesced writeout):
// A: ebuf->LDS stage + hist; B: scan (pad x4); C: LDS sort -> stage2;
// D: stage2 -> esrc int4 streams; E: per-node max/exp from sorted LDS + partial S
__global__ __launch_bounds__(512) void k_bucket(const int* __restrict__ bin_total,
                                                const int* __restrict__ ebuf,
                                                int* __restrict__ esrc,
                                                int* __restrict__ cnt,
                                                int* __restrict__ start,
                                                const float* __restrict__ s_src,
                                                const float* __restrict__ s_dst,
                                                float* __restrict__ expv,
                                                float* __restrict__ S) {
    __shared__ int stage[SCAP];
    __shared__ int stage2[SCAP];
    __shared__ int lh[128];
    __shared__ int lbase[128];
    __shared__ int lcur[128];
    __shared__ int wtot2[2];
    __shared__ float sred[8][4];
    int b = blockIdx.x, tid = threadIdx.x;
    int base = b * PCAP;
    int total = bin_total[b];
    if (total > SCAP - 512) total = SCAP - 512;   // unreachable (+23 sigma)
    if (tid < 128) lh[tid] = 0;
    __syncthreads();
    // ---- A: stage-in + histogram
    const int4* eb4 = (const int4*)(ebuf + base);
    int n4 = total >> 2;
    for (int i4 = tid; i4 < n4; i4 += 512) {
        int4 r = eb4[i4];
        int i = i4 << 2;
        stage[i] = r.x; stage[i + 1] = r.y; stage[i + 2] = r.z; stage[i + 3] = r.w;
        atomicAdd(&lh[(r.x >> 17) & 127], 1);
        atomicAdd(&lh[(r.y >> 17) & 127], 1);
        atomicAdd(&lh[(r.z >> 17) & 127], 1);
        atomicAdd(&lh[(r.w >> 17) & 127], 1);
    }
    for (int i = (n4 << 2) + tid; i < total; i += 512) {
        int rec = ebuf[base + i];
        stage[i] = rec;
        atomicAdd(&lh[(rec >> 17) & 127], 1);
    }
    __syncthreads();
    // ---- B: scan of x4-padded counts (tid<128, 2 waves)
    int val = 0, padded = 0, rel = 0;
    if (tid < 128) {
        val = lh[tid];
        padded = (val + 3) & ~3;
        int v = padded;
        int lane = tid & 63;
#pragma unroll
        for (int off = 1; off < 64; off <<= 1) {
            int t = __shfl_up(v, off);
            if (lane >= off) v += t;
        }
        if (lane == 63) wtot2[tid >> 6] = v;
        rel = v - padded;
    }
    __syncthreads();
    int binpad = wtot2[0] + wtot2[1];
    if (tid < 128) {
        if (tid >= 64) rel += wtot2[0];
        int node = b * 128 + tid;
        if (node < N_NODES) { cnt[node] = padded; start[node] = base + rel; }
        lbase[tid] = rel;
        lcur[tid] = rel;
    }
    __syncthreads();
    // ---- C: sort into stage2 (one LDS atomic per record)
    for (int i = tid; i < total; i += 512) {
        int rec = stage[i];
        int p = atomicAdd(&lcur[(rec >> 17) & 127], 1);
        stage2[p] = rec & 0x1FFFF;
    }
    __syncthreads();
    if (tid < 128) {
        for (int k = val; k < padded; k++) stage2[lbase[tid] + k] = N_NODES;  // zero-row pads
    }
    __syncthreads();
    // ---- D: coalesced writeout
    int4* es4 = (int4*)(esrc + base);
    int b4 = binpad >> 2;
    for (int i4 = tid; i4 < b4; i4 += 512) {
        int i = i4 << 2;
        es4[i4] = make_int4(stage2[i], stage2[i + 1], stage2[i + 2], stage2[i + 3]);
    }
    // ---- E: per-node segment max (4 independent gathers/step; sentinel pads)
    float4 e4 = make_float4(0.f, 0.f, 0.f, 0.f);
    if (tid < 128) {
        int node = b * 128 + tid;
        int lb = lbase[tid];
        float4 m = make_float4(-3e38f, -3e38f, -3e38f, -3e38f);
        for (int k = 0; k < padded; k += 4) {
            int s0 = stage2[lb + k], s1 = stage2[lb + k + 1];
            int s2 = stage2[lb + k + 2], s3 = stage2[lb + k + 3];
            float4 a0 = ((const float4*)s_src)[s0];
            float4 a1 = ((const float4*)s_src)[s1];
            float4 a2 = ((const float4*)s_src)[s2];
            float4 a3 = ((const float4*)s_src)[s3];
            m.x = fmaxf(fmaxf(m.x, a0.x), fmaxf(fmaxf(a1.x, a2.x), a3.x));
            m.y = fmaxf(fmaxf(m.y, a0.y), fmaxf(fmaxf(a1.y, a2.y), a3.y));
            m.z = fmaxf(fmaxf(m.z, a0.z), fmaxf(fmaxf(a1.z, a2.z), a3.z));
            m.w = fmaxf(fmaxf(m.w, a0.w), fmaxf(fmaxf(a1.w, a2.w), a3.w));
        }
        if (node < N_NODES) {
            float4 d = ((const float4*)s_dst)[node];
            float x;
            x = m.x + d.x; x = x > 0.f ? x : NEG_SLOPE * x; e4.x = __expf(x - EXP_SHIFT);
            x = m.y + d.y; x = x > 0.f ? x : NEG_SLOPE * x; e4.y = __expf(x - EXP_SHIFT);
            x = m.z + d.z; x = x > 0.f ? x : NEG_SLOPE * x; e4.z = __expf(x - EXP_SHIFT);
            x = m.w + d.w; x = x > 0.f ? x : NEG_SLOPE * x; e4.w = __expf(x - EXP_SHIFT);
            ((float4*)expv)[node] = e4;
        }
    }
    // ---- partial softmax denominator
    int lane = tid & 63, wv = tid >> 6;
#pragma unroll
    for (int off = 32; off; off >>= 1) {
        e4.x += __shfl_xor(e4.x, off);
        e4.y += __shfl_xor(e4.y, off);
        e4.z += __shfl_xor(e4.z, off);
        e4.w += __shfl_xor(e4.w, off);
    }
    if (lane == 0) { sred[wv][0] = e4.x; sred[wv][1] = e4.y; sred[wv][2] = e4.z; sred[wv][3] = e4.w; }
    __syncthreads();
    if (tid < 4) {
        float s = 0.f;
#pragma unroll
        for (int i = 0; i < 8; i++) s += sred[i][tid];
        atomicAdd(&S[tid], s);
    }
}

// ---------------- aggregate: one wave per node; scalar walk; deg is x4-padded
__global__ __launch_bounds__(256) void k_agg(const unsigned int* __restrict__ Whb32,
                                             const int* __restrict__ esrc,
                                             const int* __restrict__ start,
                                             const int* __restrict__ cnt,
                                             const float* __restrict__ expv,
                                             const float* __restrict__ S,
                                             float* __restrict__ out) {
    int node = (blockIdx.x * 256 + threadIdx.x) >> 6;
    if (node >= N_NODES) return;
    int lane = threadIdx.x & 63;
    int base = __builtin_amdgcn_readfirstlane(start[node]);
    int deg  = __builtin_amdgcn_readfirstlane(cnt[node]);
    const unsigned int* Wl = Whb32 + lane;
    float accx = 0.f, accy = 0.f;
    int i = 0;
    for (; i + 16 <= deg; i += 16) {
        unsigned int v[16];
#pragma unroll
        for (int j = 0; j < 16; j++) {
            int s = esrc[base + i + j];
            v[j] = Wl[(size_t)s * 64];
        }
#pragma unroll
        for (int j = 0; j < 16; j++) {
            accx += __uint_as_float(v[j] << 16);
            accy += __uint_as_float(v[j] & 0xffff0000u);
        }
    }
    for (; i < deg; i += 4) {
        unsigned int v[4];
#pragma unroll
        for (int j = 0; j < 4; j++) {
            int s = esrc[base + i + j];
            v[j] = Wl[(size_t)s * 64];
        }
#pragma unroll
        for (int j = 0; j < 4; j++) {
            accx += __uint_as_float(v[j] << 16);
            accy += __uint_as_float(v[j] & 0xffff0000u);
        }
    }
    int head = lane >> 4;
    float attn = expv[node * 4 + head] / S[head];
    ((float2*)out)[(size_t)node * 64 + lane] = make_float2(accx * attn, accy * attn);
}

extern "C" void kernel_launch(void* const* d_in, const int* in_sizes, int n_in,
                              void* d_out, int out_size, void* d_ws, size_t ws_size,
                              hipStream_t stream) {
    const float* h  = (const float*)d_in[0];
    const int*   ei = (const int*)d_in[1];
    const float* W  = (const float*)d_in[2];
    const float* a  = (const float*)d_in[3];
    float* out = (float*)d_out;

    char* ws = (char*)d_ws;
    unsigned short* Whb = (unsigned short*)(ws);     // 25,600,256 B (100001 rows bf16)
    float* s_src     = (float*)(ws + 25600256);      //  1,600,016 (incl sentinel row)
    float* s_dst     = (float*)(ws + 27200272);      //  1,600,000
    float* expv      = (float*)(ws + 28800272);      //  1,600,000
    int*   cnt       = (int*)  (ws + 30400272);      //    400,000
    int*   start     = (int*)  (ws + 30800272);      //    400,000
    int*   ebuf      = (int*)  (ws + 31200272);      // 12,812,288 (NB*PCAP*4)
    int*   esrc      = (int*)  (ws + 44012560);      // 12,812,288
    int*   hist      = (int*)  (ws + 56824848);      //  1,223,048 (NT*NB*4)
    int*   tileoff   = (int*)  (ws + 58047896);      //  1,223,048
    int*   bin_total = (int*)  (ws + 59270944);      //      3,128
    float* S         = (float*)(ws + 59274072);      //         16
    // Wt (32 KB bf16) aliases ebuf: live only k_prep -> k_gemm, before k_scat
    unsigned short* Wt = (unsigned short*)ebuf;

    k_prep<<<NT + 32, 256, 0, stream>>>(ei, W, Wt, hist, S, s_src);
    k_gemm<<<782, 512, 0, stream>>>(h, Wt, a, Whb, s_src, s_dst);
    k_scan<<<NB, 512, 0, stream>>>(hist, tileoff, bin_total);
    k_scat<<<NT, 256, 0, stream>>>(ei, tileoff, ebuf);
    k_bucket<<<NB, 512, 0, stream>>>(bin_total, ebuf, esrc, cnt, start,
                                     s_src, s_dst, expv, S);
    k_agg<<<25000, 256, 0, stream>>>((const unsigned int*)Whb, esrc, start, cnt, expv, S, out);
}

// Round 10
// 224.310 us; speedup vs baseline: 1.0732x; 1.0507x over previous
//
#include <hip/hip_runtime.h>
#include <hip/hip_bf16.h>
#include <float.h>

#define N_NODES 100000
#define N_EDGES 1600000
#define HEADS 4
#define OUT_F 32
#define NEG_SLOPE 0.2f
#define EXP_SHIFT 8.0f

#define NB 782      // bins of 128 nodes: bin = dst >> 7 (782*128 = 100096)
#define NT 391      // tiles of 4096 edges
#define PCAP 4096   // per-bin capacity = 8 groups x GC
#define GC 512      // per-(bin,group) sub-capacity (Poisson mean 256, +16 sigma)
#define SCAP 3072   // k_bucket LDS stage (mean 2046; clamp at SCAP-512 = +11 sigma)

typedef __attribute__((ext_vector_type(8))) short short8;
typedef __attribute__((ext_vector_type(4))) float f32x4;

__device__ __forceinline__ unsigned short f2bf(float f) {
    unsigned int u = __float_as_uint(f);
    u += 0x7fff + ((u >> 16) & 1);   // round-to-nearest-even
    return (unsigned short)(u >> 16);
}

// ---------------- prep: blocks [0,NT) per-tile coarse histogram;
//                  blocks [NT,NT+32) transpose W->Wt bf16; S=0; s_src sentinel
__global__ __launch_bounds__(256) void k_prep(const int* __restrict__ ei,
                                              const float* __restrict__ W,
                                              unsigned short* __restrict__ Wt,
                                              int* __restrict__ hist,
                                              float* __restrict__ S,
                                              float* __restrict__ s_src) {
    __shared__ int lh[NB];
    int b = blockIdx.x, tid = threadIdx.x;
    if (b < NT) {
        for (int i = tid; i < NB; i += 256) lh[i] = 0;
        __syncthreads();
        const int4* d4 = (const int4*)(ei + N_EDGES);
        int base4 = b * 1024;
#pragma unroll
        for (int it = 0; it < 4; it++) {
            int i4 = base4 + tid + 256 * it;
            if (i4 < N_EDGES / 4) {
                int4 d = d4[i4];
                atomicAdd(&lh[d.x >> 7], 1);
                atomicAdd(&lh[d.y >> 7], 1);
                atomicAdd(&lh[d.z >> 7], 1);
                atomicAdd(&lh[d.w >> 7], 1);
            }
        }
        __syncthreads();
        for (int i = tid; i < NB; i += 256) hist[b * NB + i] = lh[i];
    } else {
        int idx = (b - NT) * 256 + tid;    // 0..8191 ushort2 pairs
        int n = idx & 127, k2 = idx >> 7;  // k2 in 0..63
        float w0 = W[(size_t)(2 * k2) * 128 + n];
        float w1 = W[(size_t)(2 * k2 + 1) * 128 + n];
        *(ushort2*)&Wt[(size_t)n * 128 + 2 * k2] = make_ushort2(f2bf(w0), f2bf(w1));
        if (b == NT) {
            if (tid < 4) S[tid] = 0.0f;
            if (tid >= 4 && tid < 8) s_src[N_NODES * 4 + (tid - 4)] = -1e30f;
        }
    }
}

// ---------------- GEMM: Whb(bf16, rows 0..N_NODES incl zero pad row) = h @ W
__global__ __launch_bounds__(512) void k_gemm(const float* __restrict__ hp,
                                              const unsigned short* __restrict__ Wt,
                                              const float* __restrict__ av,
                                              unsigned short* __restrict__ Whb,
                                              float* __restrict__ s_src,
                                              float* __restrict__ s_dst) {
    __shared__ short wsB[128][136];
    int tid = threadIdx.x;
    int rowBase = blockIdx.x * 128;

    const short8* Wt8 = (const short8*)Wt;
#pragma unroll
    for (int i = 0; i < 4; i++) {
        int idx = tid + 512 * i;          // 0..2047
        int n = idx >> 4, ch = idx & 15;
        *(short8*)&wsB[n][ch * 8] = Wt8[idx];
    }
    __syncthreads();

    int lane = tid & 63;
    int wv = tid >> 6;                    // 0..7
    int l16 = lane & 15, quad = lane >> 4;

    int arow = rowBase + wv * 16 + l16;
    bool valid = arow < N_NODES;
    const float* hrow = hp + (size_t)arow * 128;
    short8 afr[4];
#pragma unroll
    for (int k4 = 0; k4 < 4; k4++) {
        float4 u0 = valid ? *(const float4*)&hrow[k4 * 32 + quad * 8]
                          : make_float4(0.f, 0.f, 0.f, 0.f);
        float4 u1 = valid ? *(const float4*)&hrow[k4 * 32 + quad * 8 + 4]
                          : make_float4(0.f, 0.f, 0.f, 0.f);
        afr[k4] = (short8){(short)f2bf(u0.x), (short)f2bf(u0.y),
                           (short)f2bf(u0.z), (short)f2bf(u0.w),
                           (short)f2bf(u1.x), (short)f2bf(u1.y),
                           (short)f2bf(u1.z), (short)f2bf(u1.w)};
    }

    f32x4 acc[8];
#pragma unroll
    for (int nt = 0; nt < 8; nt++) {
        acc[nt] = (f32x4){0.f, 0.f, 0.f, 0.f};
#pragma unroll
        for (int k4 = 0; k4 < 4; k4++) {
            short8 bfr = *(const short8*)&wsB[nt * 16 + l16][k4 * 32 + quad * 8];
            acc[nt] = __builtin_amdgcn_mfma_f32_16x16x32_bf16(afr[k4], bfr, acc[nt], 0, 0, 0);
        }
    }

    int row0 = rowBase + wv * 16 + quad * 4;
#pragma unroll
    for (int r = 0; r < 4; r++) {
        int row = row0 + r;
        if (row <= N_NODES) {             // row N_NODES = zero pad row (acc==0 there)
#pragma unroll
            for (int nt = 0; nt < 8; nt++)
                Whb[(size_t)row * 128 + nt * 16 + l16] = f2bf(acc[nt][r]);
        }
    }

    float ps[4][4], pd[4][4];
#pragma unroll
    for (int h = 0; h < 4; h++) {
        float a0s = av[h * 64 + l16];
        float a1s = av[h * 64 + 16 + l16];
        float a0d = av[h * 64 + 32 + l16];
        float a1d = av[h * 64 + 48 + l16];
#pragma unroll
        for (int r = 0; r < 4; r++) {
            ps[h][r] = acc[2 * h][r] * a0s + acc[2 * h + 1][r] * a1s;
            pd[h][r] = acc[2 * h][r] * a0d + acc[2 * h + 1][r] * a1d;
        }
    }
#pragma unroll
    for (int h = 0; h < 4; h++)
#pragma unroll
        for (int r = 0; r < 4; r++) {
#pragma unroll
            for (int off = 1; off < 16; off <<= 1) {
                ps[h][r] += __shfl_xor(ps[h][r], off);
                pd[h][r] += __shfl_xor(pd[h][r], off);
            }
        }
    if (l16 < 4) {
#pragma unroll
        for (int r = 0; r < 4; r++) {
            int row = row0 + r;
            if (row < N_NODES) {
                float vs = (l16 == 0) ? ps[0][r] : (l16 == 1) ? ps[1][r]
                         : (l16 == 2) ? ps[2][r] : ps[3][r];
                float vd = (l16 == 0) ? pd[0][r] : (l16 == 1) ? pd[1][r]
                         : (l16 == 2) ? pd[2][r] : pd[3][r];
                s_src[row * 4 + l16] = vs;
                s_dst[row * 4 + l16] = vd;
            }
        }
    }
}

// ---------------- per-bin, per-group(tile%8) exclusive prefix + group subtotals
__global__ __launch_bounds__(512) void k_scan(const int* __restrict__ hist,
                                              int* __restrict__ tileoff,
                                              int* __restrict__ subtot) {
    __shared__ int vals[NT];
    int b = blockIdx.x, tid = threadIdx.x;
    if (tid < NT) vals[tid] = hist[tid * NB + b];
    __syncthreads();
    if (tid < NT) {
        int g = tid & 7;
        int pre = 0;
        for (int t = g; t < tid; t += 8) pre += vals[t];   // <=48 LDS reads
        tileoff[tid * NB + b] = pre;
        if (tid + 8 >= NT) subtot[b * 8 + g] = pre + vals[tid];
    }
}

// ---------------- scatter records into XCD-local sub-regions:
// tile t (group g = t&7) writes only [b*PCAP + g*GC, +GC) — with round-robin
// block->XCD dispatch all writers of a line sit on one XCD (no L2 bouncing)
__global__ __launch_bounds__(256) void k_scat(const int* __restrict__ ei,
                                              const int* __restrict__ tileoff,
                                              int* __restrict__ ebuf) {
    __shared__ int lcur[NB];
    int tid = threadIdx.x, tile = blockIdx.x;
    int g = tile & 7;
    for (int i = tid; i < NB; i += 256)
        lcur[i] = i * PCAP + g * GC + tileoff[tile * NB + i];
    __syncthreads();
    const int4* s4 = (const int4*)ei;
    const int4* d4 = (const int4*)(ei + N_EDGES);
    int base4 = tile * 1024;
#pragma unroll
    for (int it = 0; it < 4; it++) {
        int i4 = base4 + tid + 256 * it;
        if (i4 < N_EDGES / 4) {
            int4 s = s4[i4];
            int4 d = d4[i4];
            int p;
            p = atomicAdd(&lcur[d.x >> 7], 1); ebuf[p] = s.x | ((d.x & 127) << 17);
            p = atomicAdd(&lcur[d.y >> 7], 1); ebuf[p] = s.y | ((d.y & 127) << 17);
            p = atomicAdd(&lcur[d.z >> 7], 1); ebuf[p] = s.z | ((d.z & 127) << 17);
            p = atomicAdd(&lcur[d.w >> 7], 1); ebuf[p] = s.w | ((d.w & 127) << 17);
        }
    }
}

// ---------------- bucket: stage-in 8 sub-chunks, hist, scan(pad x4), LDS sort,
//                  coalesced esrc writeout, per-node max/exp, partial S
__global__ __launch_bounds__(512) void k_bucket(const int* __restrict__ subtot,
                                                const int* __restrict__ ebuf,
                                                int* __restrict__ esrc,
                                                int* __restrict__ cnt,
                                                int* __restrict__ start,
                                                const float* __restrict__ s_src,
                                                const float* __restrict__ s_dst,
                                                float* __restrict__ expv,
                                                float* __restrict__ S) {
    __shared__ int stage[SCAP];
    __shared__ int stage2[SCAP];
    __shared__ int lh[128];
    __shared__ int lbase[128];
    __shared__ int lcur[128];
    __shared__ int wtot2[2];
    __shared__ float sred[8][4];
    int b = blockIdx.x, tid = threadIdx.x;
    int base = b * PCAP;
    if (tid < 128) lh[tid] = 0;
    __syncthreads();
    // ---- A: stage-in from 8 sub-regions + histogram
    int total = 0;
#pragma unroll
    for (int g = 0; g < 8; g++) {
        int c = subtot[b * 8 + g];
        if (total + c > SCAP - 512) c = SCAP - 512 - total;  // unreachable clamp
        const int* src = ebuf + base + g * GC;
        for (int i = tid; i < c; i += 512) {
            int rec = src[i];
            stage[total + i] = rec;
            atomicAdd(&lh[(rec >> 17) & 127], 1);
        }
        total += c;
    }
    __syncthreads();
    // ---- B: scan of x4-padded counts (tid<128, 2 waves)
    int val = 0, padded = 0, rel = 0;
    if (tid < 128) {
        val = lh[tid];
        padded = (val + 3) & ~3;
        int v = padded;
        int lane = tid & 63;
#pragma unroll
        for (int off = 1; off < 64; off <<= 1) {
            int t = __shfl_up(v, off);
            if (lane >= off) v += t;
        }
        if (lane == 63) wtot2[tid >> 6] = v;
        rel = v - padded;
    }
    __syncthreads();
    int binpad = wtot2[0] + wtot2[1];
    if (tid < 128) {
        if (tid >= 64) rel += wtot2[0];
        int node = b * 128 + tid;
        if (node < N_NODES) { cnt[node] = padded; start[node] = base + rel; }
        lbase[tid] = rel;
        lcur[tid] = rel;
    }
    __syncthreads();
    // ---- C: sort into stage2 (one LDS atomic per record)
    for (int i = tid; i < total; i += 512) {
        int rec = stage[i];
        int p = atomicAdd(&lcur[(rec >> 17) & 127], 1);
        stage2[p] = rec & 0x1FFFF;
    }
    __syncthreads();
    if (tid < 128) {
        for (int k = val; k < padded; k++) stage2[lbase[tid] + k] = N_NODES;  // zero-row pads
    }
    __syncthreads();
    // ---- D: coalesced writeout
    int4* es4 = (int4*)(esrc + base);
    int b4 = binpad >> 2;
    for (int i4 = tid; i4 < b4; i4 += 512) {
        int i = i4 << 2;
        es4[i4] = make_int4(stage2[i], stage2[i + 1], stage2[i + 2], stage2[i + 3]);
    }
    // ---- E: per-node segment max (4 independent gathers/step; sentinel pads)
    float4 e4 = make_float4(0.f, 0.f, 0.f, 0.f);
    if (tid < 128) {
        int node = b * 128 + tid;
        int lb = lbase[tid];
        float4 m = make_float4(-3e38f, -3e38f, -3e38f, -3e38f);
        for (int k = 0; k < padded; k += 4) {
            int s0 = stage2[lb + k], s1 = stage2[lb + k + 1];
            int s2 = stage2[lb + k + 2], s3 = stage2[lb + k + 3];
            float4 a0 = ((const float4*)s_src)[s0];
            float4 a1 = ((const float4*)s_src)[s1];
            float4 a2 = ((const float4*)s_src)[s2];
            float4 a3 = ((const float4*)s_src)[s3];
            m.x = fmaxf(fmaxf(m.x, a0.x), fmaxf(fmaxf(a1.x, a2.x), a3.x));
            m.y = fmaxf(fmaxf(m.y, a0.y), fmaxf(fmaxf(a1.y, a2.y), a3.y));
            m.z = fmaxf(fmaxf(m.z, a0.z), fmaxf(fmaxf(a1.z, a2.z), a3.z));
            m.w = fmaxf(fmaxf(m.w, a0.w), fmaxf(fmaxf(a1.w, a2.w), a3.w));
        }
        if (node < N_NODES) {
            float4 d = ((const float4*)s_dst)[node];
            float x;
            x = m.x + d.x; x = x > 0.f ? x : NEG_SLOPE * x; e4.x = __expf(x - EXP_SHIFT);
            x = m.y + d.y; x = x > 0.f ? x : NEG_SLOPE * x; e4.y = __expf(x - EXP_SHIFT);
            x = m.z + d.z; x = x > 0.f ? x : NEG_SLOPE * x; e4.z = __expf(x - EXP_SHIFT);
            x = m.w + d.w; x = x > 0.f ? x : NEG_SLOPE * x; e4.w = __expf(x - EXP_SHIFT);
            ((float4*)expv)[node] = e4;
        }
    }
    // ---- partial softmax denominator
    int lane = tid & 63, wv = tid >> 6;
#pragma unroll
    for (int off = 32; off; off >>= 1) {
        e4.x += __shfl_xor(e4.x, off);
        e4.y += __shfl_xor(e4.y, off);
        e4.z += __shfl_xor(e4.z, off);
        e4.w += __shfl_xor(e4.w, off);
    }
    if (lane == 0) { sred[wv][0] = e4.x; sred[wv][1] = e4.y; sred[wv][2] = e4.z; sred[wv][3] = e4.w; }
    __syncthreads();
    if (tid < 4) {
        float s = 0.f;
#pragma unroll
        for (int i = 0; i < 8; i++) s += sred[i][tid];
        atomicAdd(&S[tid], s);
    }
}

// ---------------- aggregate: one wave per node; scalar walk; deg is x4-padded
__global__ __launch_bounds__(256) void k_agg(const unsigned int* __restrict__ Whb32,
                                             const int* __restrict__ esrc,
                                             const int* __restrict__ start,
                                             const int* __restrict__ cnt,
                                             const float* __restrict__ expv,
                                             const float* __restrict__ S,
                                             float* __restrict__ out) {
    int node = (blockIdx.x * 256 + threadIdx.x) >> 6;
    if (node >= N_NODES) return;
    int lane = threadIdx.x & 63;
    int base = __builtin_amdgcn_readfirstlane(start[node]);
    int deg  = __builtin_amdgcn_readfirstlane(cnt[node]);
    const unsigned int* Wl = Whb32 + lane;
    float accx = 0.f, accy = 0.f;
    int i = 0;
    for (; i + 16 <= deg; i += 16) {
        unsigned int v[16];
#pragma unroll
        for (int j = 0; j < 16; j++) {
            int s = esrc[base + i + j];
            v[j] = Wl[(size_t)s * 64];
        }
#pragma unroll
        for (int j = 0; j < 16; j++) {
            accx += __uint_as_float(v[j] << 16);
            accy += __uint_as_float(v[j] & 0xffff0000u);
        }
    }
    for (; i < deg; i += 4) {
        unsigned int v[4];
#pragma unroll
        for (int j = 0; j < 4; j++) {
            int s = esrc[base + i + j];
            v[j] = Wl[(size_t)s * 64];
        }
#pragma unroll
        for (int j = 0; j < 4; j++) {
            accx += __uint_as_float(v[j] << 16);
            accy += __uint_as_float(v[j] & 0xffff0000u);
        }
    }
    int head = lane >> 4;
    float attn = expv[node * 4 + head] / S[head];
    ((float2*)out)[(size_t)node * 64 + lane] = make_float2(accx * attn, accy * attn);
}

extern "C" void kernel_launch(void* const* d_in, const int* in_sizes, int n_in,
                              void* d_out, int out_size, void* d_ws, size_t ws_size,
                              hipStream_t stream) {
    const float* h  = (const float*)d_in[0];
    const int*   ei = (const int*)d_in[1];
    const float* W  = (const float*)d_in[2];
    const float* a  = (const float*)d_in[3];
    float* out = (float*)d_out;

    char* ws = (char*)d_ws;
    unsigned short* Whb = (unsigned short*)(ws);     // 25,600,256 B (100001 rows bf16)
    float* s_src     = (float*)(ws + 25600256);      //  1,600,016 (incl sentinel row)
    float* s_dst     = (float*)(ws + 27200272);      //  1,600,000
    float* expv      = (float*)(ws + 28800272);      //  1,600,000
    int*   cnt       = (int*)  (ws + 30400272);      //    400,000
    int*   start     = (int*)  (ws + 30800272);      //    400,000
    int*   ebuf      = (int*)  (ws + 31200272);      // 12,812,288 (NB*PCAP*4)
    int*   esrc      = (int*)  (ws + 44012560);      // 12,812,288
    int*   hist      = (int*)  (ws + 56824848);      //  1,223,048 (NT*NB*4)
    int*   tileoff   = (int*)  (ws + 58047896);      //  1,223,048
    int*   subtot    = (int*)  (ws + 59270944);      //     25,024 (NB*8*4)
    float* S         = (float*)(ws + 59295968);      //         16
    // Wt (32 KB bf16) aliases ebuf: live only k_prep -> k_gemm, before k_scat
    unsigned short* Wt = (unsigned short*)ebuf;

    k_prep<<<NT + 32, 256, 0, stream>>>(ei, W, Wt, hist, S, s_src);
    k_gemm<<<782, 512, 0, stream>>>(h, Wt, a, Whb, s_src, s_dst);
    k_scan<<<NB, 512, 0, stream>>>(hist, tileoff, subtot);
    k_scat<<<NT, 256, 0, stream>>>(ei, tileoff, ebuf);
    k_bucket<<<NB, 512, 0, stream>>>(subtot, ebuf, esrc, cnt, start,
                                     s_src, s_dst, expv, S);
    k_agg<<<25000, 256, 0, stream>>>((const unsigned int*)Whb, esrc, start, cnt, expv, S, out);
}